// Round 8
// baseline (457.524 us; speedup 1.0000x reference)
//
#include <hip/hip_runtime.h>
#include <stdint.h>

#define HH 512
#define WW 512
#define CIN 64
#define COUT 128
#define NB 4
#define STRIP 128
#define NXS (WW / STRIP)            // 4 x-strips
#define NBINS (NB * HH * NXS)       // 8192 bins: (b, input-row, strip)
#define SCOLS 130                   // staged cols (128 + 2 halo)
#define SLAB_B (SCOLS * CIN * 2)    // 16640 B per row-slab

typedef __bf16 bf16x8 __attribute__((ext_vector_type(8)));
typedef float f32x4 __attribute__((ext_vector_type(4)));

__device__ __forceinline__ unsigned short f2bf(float f) {
    union { float f; uint32_t u; } v; v.f = f;
    uint32_t u = v.u;
    u += 0x7fffu + ((u >> 16) & 1u);   // RNE
    return (unsigned short)(u >> 16);
}
__device__ __forceinline__ float bf2f(uint32_t u) {
    union { uint32_t u; float f; } v; v.u = u << 16;
    return v.f;
}

// Fused: per-bin point count (atomic) + weight transform.
// Wt2 layout: [(k>>3)][co][k&7] bf16, k = (ky*3+kx)*64 + ci.
__global__ void count_wt_kernel(const int* __restrict__ coors, int npts,
                                int* __restrict__ cnt,
                                const float* __restrict__ w,
                                unsigned short* __restrict__ wt2) {
    int t = blockIdx.x * 256 + threadIdx.x;
    if (t < npts) {
        int b = coors[t * 3 + 0];
        int y = coors[t * 3 + 1];
        int x = coors[t * 3 + 2];
        atomicAdd(&cnt[((b << 9) + y) * NXS + (x >> 7)], 1);
    }
    if (t < COUT * 576) {
        int co = t / 576;
        int k  = t - co * 576;
        int off = k >> 6;
        int ci  = k & 63;
        int ky = off / 3;
        int kx = off - ky * 3;
        float val = w[((co * CIN + ci) * 3 + ky) * 3 + kx];
        wt2[(size_t)(k >> 3) * (COUT * 8) + co * 8 + (k & 7)] = f2bf(val);
    }
}

// Exclusive scan of 8192 bin counts -> off[] (+ total at off[NBINS]) and cur[].
__global__ void scan_kernel(const int* __restrict__ cnt,
                            int* __restrict__ off, int* __restrict__ cur) {
    __shared__ int part[256];
    int t = threadIdx.x;
    int base = t * 32;
    int s = 0;
    for (int i = 0; i < 32; ++i) s += cnt[base + i];
    part[t] = s;
    __syncthreads();
    if (t == 0) {
        int run = 0;
        for (int i = 0; i < 256; ++i) { int v = part[i]; part[i] = run; run += v; }
        off[NBINS] = run;
    }
    __syncthreads();
    int run = part[t];
    for (int i = 0; i < 32; ++i) {
        int bin = base + i;
        int v = cnt[bin];
        off[bin] = run;
        cur[bin] = run;
        run += v;
    }
}

// CSR fill: idx[pos] = point-id | (x << 18)  (p < 2^18, x < 2^9).
__global__ void fill_kernel(const int* __restrict__ coors, int npts,
                            int* __restrict__ cur, int* __restrict__ idx) {
    int p = blockIdx.x * 256 + threadIdx.x;
    if (p >= npts) return;
    int b = coors[p * 3 + 0];
    int y = coors[p * 3 + 1];
    int x = coors[p * 3 + 2];
    int bin = ((b << 9) + y) * NXS + (x >> 7);
    int pos = atomicAdd(&cur[bin], 1);
    idx[pos] = p | (x << 18);
}

// Sparse-direct conv block: (batch, output row y, 128-site strip), all 128 co.
// LDS input tile composed directly from the point CSR: zero 3 row-slabs,
// wave w (<3) serially scatter-adds its row's points into the swizzled
// layout (same involution as R5's verified global_load_lds scheme), then
// the R5 K-loop: 4 waves x (64 sites x 64 co), 16x16x32 MFMA, f32x4 stores.
__global__ __launch_bounds__(256, 3) void conv_kernel(
        const float* __restrict__ feat,
        const int* __restrict__ off,
        const int* __restrict__ idx,
        const __bf16* __restrict__ wt2,
        float* __restrict__ out) {
    __shared__ __align__(16) __bf16 lds[3 * SCOLS * CIN];

    const int bid = blockIdx.x;
    const int xs = bid & 3;
    const int y  = (bid >> 2) & 511;
    const int b  = bid >> 11;
    const int x0 = xs * STRIP;
    const int tid = threadIdx.x;
    const int wave = tid >> 6;
    const int lane = tid & 63;
    const int lhi = lane >> 4;
    const int llo = lane & 15;
    const int site_base = (wave & 1) * 64;
    const int co_base   = (wave >> 1) * 64;

    // zero all 3 slabs (49,920 B)
    {
        const int n16 = 3 * SLAB_B / 16;   // 3120 16B units
        f32x4* l4 = reinterpret_cast<f32x4*>(lds);
        for (int i = tid; i < n16; i += 256)
            l4[i] = (f32x4){0.f, 0.f, 0.f, 0.f};
    }
    __syncthreads();

    // gather: wave w stages input row y-1+w from bins (xs-1, xs, xs+1)
    const int irow = y - 1 + wave;
    if (wave < 3 && (unsigned)irow < HH) {
        char* slab = (char*)lds + wave * SLAB_B;
        const int binrow = ((b << 9) + irow) * NXS;
        #pragma unroll
        for (int nb = -1; nb <= 1; ++nb) {
            int xsn = xs + nb;
            if ((unsigned)xsn < NXS) {
                int s = off[binrow + xsn];
                int e = off[binrow + xsn + 1];
                for (int j = s; j < e; ++j) {
                    int v = idx[j];
                    int xp = v >> 18;
                    int col = xp + 1 - x0;             // window [0, 129]
                    if ((unsigned)col <= 129u && lane < 32) {
                        int p = v & 0x3ffff;
                        int o = lane << 2;             // u32 byte offset in row
                        uint32_t* slot = (uint32_t*)(slab + col * 128
                                                     + (o ^ ((col & 7) << 4)));
                        float fx = feat[(size_t)p * CIN + lane * 2];
                        float fy = feat[(size_t)p * CIN + lane * 2 + 1];
                        uint32_t c = *slot;
                        uint32_t nx = f2bf(bf2f(c & 0xffffu) + fx);
                        uint32_t ny = f2bf(bf2f(c >> 16) + fy);
                        *slot = nx | (ny << 16);
                    }
                }
            }
        }
    }
    __syncthreads();

    f32x4 acc[4][4];
    #pragma unroll
    for (int mt = 0; mt < 4; ++mt)
        #pragma unroll
        for (int nt = 0; nt < 4; ++nt)
            acc[mt][nt] = (f32x4){0.f, 0.f, 0.f, 0.f};

    #pragma unroll
    for (int off9 = 0; off9 < 9; ++off9) {
        const int ky = off9 / 3;
        const int kx = off9 - ky * 3;
        const char* slab = (const char*)lds + ky * SLAB_B;
        #pragma unroll
        for (int ch = 0; ch < 2; ++ch) {
            bf16x8 a[4];
            #pragma unroll
            for (int mt = 0; mt < 4; ++mt) {
                int col = site_base + mt * 16 + llo + kx;
                int eb = (ch * 64 + lhi * 16) ^ ((col & 7) << 4);
                a[mt] = *reinterpret_cast<const bf16x8*>(slab + col * 128 + eb);
            }
            const __bf16* bb = wt2 + (size_t)(off9 * 8 + ch * 4 + lhi) * (COUT * 8);
            #pragma unroll
            for (int nt = 0; nt < 4; ++nt) {
                bf16x8 bw = *reinterpret_cast<const bf16x8*>(
                    &bb[(co_base + nt * 16 + llo) * 8]);
                #pragma unroll
                for (int mt = 0; mt < 4; ++mt)
                    acc[mt][nt] = __builtin_amdgcn_mfma_f32_16x16x32_bf16(
                        a[mt], bw, acc[mt][nt], 0, 0, 0);
            }
        }
    }

    // D mapping: col(llo)=co, row(lhi*4+q)=site -> reg quad = 4 consecutive x
    #pragma unroll
    for (int nt = 0; nt < 4; ++nt) {
        int co = co_base + nt * 16 + llo;
        float* orow = out + ((size_t)(b * COUT + co) * HH + y) * WW
                          + x0 + site_base + lhi * 4;
        #pragma unroll
        for (int mt = 0; mt < 4; ++mt)
            __builtin_nontemporal_store(acc[mt][nt],
                reinterpret_cast<f32x4*>(&orow[mt * 16]));
    }
}

extern "C" void kernel_launch(void* const* d_in, const int* in_sizes, int n_in,
                              void* d_out, int out_size, void* d_ws, size_t ws_size,
                              hipStream_t stream) {
    const float* feat  = (const float*)d_in[0];
    const int*   coors = (const int*)d_in[1];
    const float* w     = (const float*)d_in[3];
    float* out = (float*)d_out;

    const int npts = in_sizes[0] / CIN;   // 200000

    int* cnt = (int*)d_ws;
    int* off = cnt + NBINS;
    int* cur = off + NBINS + 1;
    int* idx = cur + NBINS;
    uintptr_t wa = (uintptr_t)(idx + npts);
    wa = (wa + 15) & ~(uintptr_t)15;
    unsigned short* wt2 = (unsigned short*)wa;

    hipMemsetAsync(cnt, 0, NBINS * sizeof(int), stream);

    int cw_grid = (npts > COUT * 576 ? npts : COUT * 576);
    hipLaunchKernelGGL(count_wt_kernel, dim3((cw_grid + 255) / 256), dim3(256), 0, stream,
                       coors, npts, cnt, w, wt2);
    hipLaunchKernelGGL(scan_kernel, dim3(1), dim3(256), 0, stream,
                       cnt, off, cur);
    hipLaunchKernelGGL(fill_kernel, dim3((npts + 255) / 256), dim3(256), 0, stream,
                       coors, npts, cur, idx);
    hipLaunchKernelGGL(conv_kernel, dim3(NB * HH * NXS), dim3(256), 0, stream,
                       feat, off, idx, (const __bf16*)wt2, out);
}

// Round 9
// 411.368 us; speedup vs baseline: 1.1122x; 1.1122x over previous
//
#include <hip/hip_runtime.h>
#include <stdint.h>

#define HH 512
#define WW 512
#define CIN 64
#define COUT 128
#define NB 4
#define STRIP 128
#define NXS (WW / STRIP)            // 4 x-strips
#define NBINS (NB * HH * NXS)       // 8192 bins: (b, input-row, strip)
#define SCOLS 130                   // staged cols (128 + 2 halo)
#define SLAB_B (SCOLS * CIN * 2)    // 16640 B per row-slab

typedef __bf16 bf16x8 __attribute__((ext_vector_type(8)));
typedef float f32x4 __attribute__((ext_vector_type(4)));

__device__ __forceinline__ unsigned short f2bf(float f) {
    union { float f; uint32_t u; } v; v.f = f;
    uint32_t u = v.u;
    u += 0x7fffu + ((u >> 16) & 1u);   // RNE
    return (unsigned short)(u >> 16);
}
__device__ __forceinline__ float bf2f(uint32_t u) {
    union { uint32_t u; float f; } v; v.u = u << 16;
    return v.f;
}

// Fused: per-bin point count (atomic) + weight transform.
// Wt2 layout: [(k>>3)][co][k&7] bf16, k = (ky*3+kx)*64 + ci.
__global__ void count_wt_kernel(const int* __restrict__ coors, int npts,
                                int* __restrict__ cnt,
                                const float* __restrict__ w,
                                unsigned short* __restrict__ wt2) {
    int t = blockIdx.x * 256 + threadIdx.x;
    if (t < npts) {
        int b = coors[t * 3 + 0];
        int y = coors[t * 3 + 1];
        int x = coors[t * 3 + 2];
        atomicAdd(&cnt[((b << 9) + y) * NXS + (x >> 7)], 1);
    }
    if (t < COUT * 576) {
        int co = t / 576;
        int k  = t - co * 576;
        int off = k >> 6;
        int ci  = k & 63;
        int ky = off / 3;
        int kx = off - ky * 3;
        float val = w[((co * CIN + ci) * 3 + ky) * 3 + kx];
        wt2[(size_t)(k >> 3) * (COUT * 8) + co * 8 + (k & 7)] = f2bf(val);
    }
}

// Exclusive scan of 8192 bin counts -> off[] (+ total) and cur[].
__global__ void scan_kernel(const int* __restrict__ cnt,
                            int* __restrict__ off, int* __restrict__ cur) {
    __shared__ int part[256];
    int t = threadIdx.x;
    int base = t * 32;
    int s = 0;
    for (int i = 0; i < 32; ++i) s += cnt[base + i];
    part[t] = s;
    __syncthreads();
    if (t == 0) {
        int run = 0;
        for (int i = 0; i < 256; ++i) { int v = part[i]; part[i] = run; run += v; }
        off[NBINS] = run;
    }
    __syncthreads();
    int run = part[t];
    for (int i = 0; i < 32; ++i) {
        int bin = base + i;
        int v = cnt[bin];
        off[bin] = run;
        cur[bin] = run;
        run += v;
    }
}

// CSR fill: idx[pos] = point-id | (x << 18)  (p < 2^18, x < 2^9).
__global__ void fill_kernel(const int* __restrict__ coors, int npts,
                            int* __restrict__ cur, int* __restrict__ idx) {
    int p = blockIdx.x * 256 + threadIdx.x;
    if (p >= npts) return;
    int b = coors[p * 3 + 0];
    int y = coors[p * 3 + 1];
    int x = coors[p * 3 + 2];
    int bin = ((b << 9) + y) * NXS + (x >> 7);
    int pos = atomicAdd(&cur[bin], 1);
    idx[pos] = p | (x << 18);
}

// Sparse-direct conv block: (batch, output row y, 128-site strip), all 128 co.
// LDS input tile composed directly from the point CSR. Gather is parallel
// across all 8 half-waves (rows share halves 3/3/2); duplicate-column races
// handled by LDS atomicCAS on packed bf16x2. Then the verified R5 K-loop:
// 4 waves x (64 sites x 64 co), 16x16x32 MFMA, plain f32x4 stores (no nt:
// nt 64B-granule stores caused 1.26-1.6x HBM write amplification, R6/R8).
__global__ __launch_bounds__(256, 3) void conv_kernel(
        const float* __restrict__ feat,
        const int* __restrict__ off,
        const int* __restrict__ idx,
        const __bf16* __restrict__ wt2,
        float* __restrict__ out) {
    __shared__ __align__(16) __bf16 lds[3 * SCOLS * CIN];

    const int bid = blockIdx.x;
    const int xs = bid & 3;
    const int y  = (bid >> 2) & 511;
    const int b  = bid >> 11;
    const int x0 = xs * STRIP;
    const int tid = threadIdx.x;
    const int wave = tid >> 6;
    const int lane = tid & 63;
    const int lhi = lane >> 4;
    const int llo = lane & 15;
    const int site_base = (wave & 1) * 64;
    const int co_base   = (wave >> 1) * 64;

    // zero all 3 slabs
    {
        const int n16 = 3 * SLAB_B / 16;   // 3120 16B units
        f32x4* l4 = reinterpret_cast<f32x4*>(lds);
        for (int i = tid; i < n16; i += 256)
            l4[i] = (f32x4){0.f, 0.f, 0.f, 0.f};
    }
    __syncthreads();

    // parallel gather: 8 half-waves; rows 0,1,2 get 3,3,2 halves.
    {
        const int h  = tid >> 5;     // 0..7
        const int l5 = tid & 31;     // channel-pair
        int r, q, nq;
        if (h < 3)      { r = 0; q = h;     nq = 3; }
        else if (h < 6) { r = 1; q = h - 3; nq = 3; }
        else            { r = 2; q = h - 6; nq = 2; }
        const int irow = y - 1 + r;
        if ((unsigned)irow < HH) {
            char* slab = (char*)lds + r * SLAB_B;
            const int binrow = ((b << 9) + irow) * NXS;
            const int xlo = xs > 0 ? xs - 1 : 0;
            const int xhi = xs < NXS - 1 ? xs + 1 : xs;
            const int s = off[binrow + xlo];
            const int e = off[binrow + xhi + 1];
            for (int j = s + q; j < e; j += nq) {
                int v = idx[j];
                int xp = v >> 18;
                int col = xp + 1 - x0;               // window [0, 129]
                if ((unsigned)col <= 129u) {
                    int p = v & 0x3ffff;
                    uint32_t* slot = (uint32_t*)(slab + col * 128
                                                 + ((l5 << 2) ^ ((col & 7) << 4)));
                    float fx = feat[(size_t)p * CIN + l5 * 2];
                    float fy = feat[(size_t)p * CIN + l5 * 2 + 1];
                    uint32_t old = *slot;
                    while (true) {
                        uint32_t nv = (uint32_t)f2bf(bf2f(old & 0xffffu) + fx)
                                    | ((uint32_t)f2bf(bf2f(old >> 16) + fy) << 16);
                        uint32_t got = atomicCAS(slot, old, nv);
                        if (got == old) break;
                        old = got;
                    }
                }
            }
        }
    }
    __syncthreads();

    f32x4 acc[4][4];
    #pragma unroll
    for (int mt = 0; mt < 4; ++mt)
        #pragma unroll
        for (int nt = 0; nt < 4; ++nt)
            acc[mt][nt] = (f32x4){0.f, 0.f, 0.f, 0.f};

    #pragma unroll
    for (int off9 = 0; off9 < 9; ++off9) {
        const int ky = off9 / 3;
        const int kx = off9 - ky * 3;
        const char* slab = (const char*)lds + ky * SLAB_B;
        #pragma unroll
        for (int ch = 0; ch < 2; ++ch) {
            bf16x8 a[4];
            #pragma unroll
            for (int mt = 0; mt < 4; ++mt) {
                int col = site_base + mt * 16 + llo + kx;
                int eb = (ch * 64 + lhi * 16) ^ ((col & 7) << 4);
                a[mt] = *reinterpret_cast<const bf16x8*>(slab + col * 128 + eb);
            }
            const __bf16* bb = wt2 + (size_t)(off9 * 8 + ch * 4 + lhi) * (COUT * 8);
            #pragma unroll
            for (int nt = 0; nt < 4; ++nt) {
                bf16x8 bw = *reinterpret_cast<const bf16x8*>(
                    &bb[(co_base + nt * 16 + llo) * 8]);
                #pragma unroll
                for (int mt = 0; mt < 4; ++mt)
                    acc[mt][nt] = __builtin_amdgcn_mfma_f32_16x16x32_bf16(
                        a[mt], bw, acc[mt][nt], 0, 0, 0);
            }
        }
    }

    // D mapping: col(llo)=co, row(lhi*4+q)=site -> reg quad = 4 consecutive x
    #pragma unroll
    for (int nt = 0; nt < 4; ++nt) {
        int co = co_base + nt * 16 + llo;
        float* orow = out + ((size_t)(b * COUT + co) * HH + y) * WW
                          + x0 + site_base + lhi * 4;
        #pragma unroll
        for (int mt = 0; mt < 4; ++mt)
            *reinterpret_cast<f32x4*>(&orow[mt * 16]) = acc[mt][nt];
    }
}

extern "C" void kernel_launch(void* const* d_in, const int* in_sizes, int n_in,
                              void* d_out, int out_size, void* d_ws, size_t ws_size,
                              hipStream_t stream) {
    const float* feat  = (const float*)d_in[0];
    const int*   coors = (const int*)d_in[1];
    const float* w     = (const float*)d_in[3];
    float* out = (float*)d_out;

    const int npts = in_sizes[0] / CIN;   // 200000

    int* cnt = (int*)d_ws;
    int* off = cnt + NBINS;
    int* cur = off + NBINS + 1;
    int* idx = cur + NBINS;
    uintptr_t wa = (uintptr_t)(idx + npts);
    wa = (wa + 15) & ~(uintptr_t)15;
    unsigned short* wt2 = (unsigned short*)wa;

    hipMemsetAsync(cnt, 0, NBINS * sizeof(int), stream);

    int cw_grid = (npts > COUT * 576 ? npts : COUT * 576);
    hipLaunchKernelGGL(count_wt_kernel, dim3((cw_grid + 255) / 256), dim3(256), 0, stream,
                       coors, npts, cnt, w, wt2);
    hipLaunchKernelGGL(scan_kernel, dim3(1), dim3(256), 0, stream,
                       cnt, off, cur);
    hipLaunchKernelGGL(fill_kernel, dim3((npts + 255) / 256), dim3(256), 0, stream,
                       coors, npts, cur, idx);
    hipLaunchKernelGGL(conv_kernel, dim3(NB * HH * NXS), dim3(256), 0, stream,
                       feat, off, idx, (const __bf16*)wt2, out);
}

// Round 10
// 361.720 us; speedup vs baseline: 1.2649x; 1.1373x over previous
//
#include <hip/hip_runtime.h>
#include <stdint.h>

#define HH 512
#define WW 512
#define CIN 64
#define COUT 128
#define NB 4
#define STRIP 128
#define NXS (WW / STRIP)            // 4 x-strips
#define NBINS (NB * HH * NXS)       // 8192 bins: (b, input-row, strip)
#define SCOLS 130                   // staged cols (128 + 2 halo)
#define SLAB_B (SCOLS * CIN * 2)    // 16640 B per row-slab

typedef __bf16 bf16x8 __attribute__((ext_vector_type(8)));
typedef float f32x4 __attribute__((ext_vector_type(4)));

__device__ __forceinline__ unsigned short f2bf(float f) {
    union { float f; uint32_t u; } v; v.f = f;
    uint32_t u = v.u;
    u += 0x7fffu + ((u >> 16) & 1u);   // RNE
    return (unsigned short)(u >> 16);
}
__device__ __forceinline__ float bf2f(uint32_t u) {
    union { uint32_t u; float f; } v; v.u = u << 16;
    return v.f;
}

// Fused: per-bin point count (atomic) + weight transform.
// Wt2 layout: [(k>>3)][co][k&7] bf16, k = (ky*3+kx)*64 + ci.
__global__ void count_wt_kernel(const int* __restrict__ coors, int npts,
                                int* __restrict__ cnt,
                                const float* __restrict__ w,
                                unsigned short* __restrict__ wt2) {
    int t = blockIdx.x * 256 + threadIdx.x;
    if (t < npts) {
        int b = coors[t * 3 + 0];
        int y = coors[t * 3 + 1];
        int x = coors[t * 3 + 2];
        atomicAdd(&cnt[((b << 9) + y) * NXS + (x >> 7)], 1);
    }
    if (t < COUT * 576) {
        int co = t / 576;
        int k  = t - co * 576;
        int off = k >> 6;
        int ci  = k & 63;
        int ky = off / 3;
        int kx = off - ky * 3;
        float val = w[((co * CIN + ci) * 3 + ky) * 3 + kx];
        wt2[(size_t)(k >> 3) * (COUT * 8) + co * 8 + (k & 7)] = f2bf(val);
    }
}

// Exclusive scan of 8192 bin counts -> off[] (+ total) and cur[].
__global__ void scan_kernel(const int* __restrict__ cnt,
                            int* __restrict__ off, int* __restrict__ cur) {
    __shared__ int part[256];
    int t = threadIdx.x;
    int base = t * 32;
    int s = 0;
    for (int i = 0; i < 32; ++i) s += cnt[base + i];
    part[t] = s;
    __syncthreads();
    if (t == 0) {
        int run = 0;
        for (int i = 0; i < 256; ++i) { int v = part[i]; part[i] = run; run += v; }
        off[NBINS] = run;
    }
    __syncthreads();
    int run = part[t];
    for (int i = 0; i < 32; ++i) {
        int bin = base + i;
        int v = cnt[bin];
        off[bin] = run;
        cur[bin] = run;
        run += v;
    }
}

// CSR fill: idx[pos] = point-id | (x << 18)  (p < 2^18, x < 2^9).
__global__ void fill_kernel(const int* __restrict__ coors, int npts,
                            int* __restrict__ cur, int* __restrict__ idx) {
    int p = blockIdx.x * 256 + threadIdx.x;
    if (p >= npts) return;
    int b = coors[p * 3 + 0];
    int y = coors[p * 3 + 1];
    int x = coors[p * 3 + 2];
    int bin = ((b << 9) + y) * NXS + (x >> 7);
    int pos = atomicAdd(&cur[bin], 1);
    idx[pos] = p | (x << 18);
}

// Sparse-direct conv block: (batch, output row y, 128-site strip), all 128 co.
// Gather v2 (ILP): per row, one wave; 64 CSR entries per coalesced load;
// 2 points per step across 64 lanes (hi half selects point, lane&31 the
// channel-pair); unroll-4 keeps 8 points' feat loads in flight. Duplicate
// columns resolved by LDS CAS (uncontended: single iteration).
// Then the verified K-loop: 4 waves x (64 sites x 64 co), 16x16x32 MFMA,
// swizzled conflict-free ds_read, plain f32x4 stores (no nt: R6/R8 showed
// nt 64B stores cause 1.3-1.6x HBM write amplification).
__global__ __launch_bounds__(256, 3) void conv_kernel(
        const float* __restrict__ feat,
        const int* __restrict__ off,
        const int* __restrict__ idx,
        const __bf16* __restrict__ wt2,
        float* __restrict__ out) {
    __shared__ __align__(16) __bf16 lds[3 * SCOLS * CIN];

    const int bid = blockIdx.x;
    const int xs = bid & 3;
    const int y  = (bid >> 2) & 511;
    const int b  = bid >> 11;
    const int x0 = xs * STRIP;
    const int tid = threadIdx.x;
    const int wave = tid >> 6;
    const int lane = tid & 63;
    const int lhi = lane >> 4;
    const int llo = lane & 15;
    const int site_base = (wave & 1) * 64;
    const int co_base   = (wave >> 1) * 64;

    // zero all 3 slabs
    {
        const int n16 = 3 * SLAB_B / 16;   // 3120 16B units
        f32x4* l4 = reinterpret_cast<f32x4*>(lds);
        for (int i = tid; i < n16; i += 256)
            l4[i] = (f32x4){0.f, 0.f, 0.f, 0.f};
    }
    __syncthreads();

    // ---- gather: wave r stages input row y-1+r (waves 0..2; wave 3 idle)
    if (wave < 3) {
        const int irow = y - 1 + wave;
        if ((unsigned)irow < HH) {
            char* slab = (char*)lds + wave * SLAB_B;
            const int binrow = ((b << 9) + irow) * NXS;
            const int xlo = xs > 0 ? xs - 1 : 0;
            const int xhi = xs < NXS - 1 ? xs + 1 : xs;
            const int s = off[binrow + xlo];
            const int e = off[binrow + xhi + 1];
            const int hi = lane >> 5;          // which point of the pair
            const int c2 = lane & 31;          // channel-pair
            for (int base = s; base < e; base += 64) {
                const int nchunk = e - base < 64 ? e - base : 64;
                int j = base + lane;
                int v = (j < e) ? idx[j] : 0;  // coalesced chunk load
                #pragma unroll 4
                for (int t = 0; t < 64; t += 2) {
                    if (t >= nchunk) break;
                    int vp = __shfl(v, t + hi);
                    int xp = vp >> 18;
                    int col = xp + 1 - x0;     // window [0, 129]
                    bool ok = (t + hi) < nchunk && (unsigned)col <= 129u;
                    if (ok) {
                        int p = vp & 0x3ffff;
                        float2 f = *reinterpret_cast<const float2*>(
                            &feat[(size_t)p * CIN + c2 * 2]);
                        uint32_t* slot = (uint32_t*)(slab + col * 128
                                                     + ((c2 << 2) ^ ((col & 7) << 4)));
                        uint32_t old = *slot;
                        while (true) {
                            uint32_t nv = (uint32_t)f2bf(bf2f(old & 0xffffu) + f.x)
                                        | ((uint32_t)f2bf(bf2f(old >> 16) + f.y) << 16);
                            uint32_t got = atomicCAS(slot, old, nv);
                            if (got == old) break;
                            old = got;
                        }
                    }
                }
            }
        }
    }
    __syncthreads();

    f32x4 acc[4][4];
    #pragma unroll
    for (int mt = 0; mt < 4; ++mt)
        #pragma unroll
        for (int nt = 0; nt < 4; ++nt)
            acc[mt][nt] = (f32x4){0.f, 0.f, 0.f, 0.f};

    #pragma unroll
    for (int off9 = 0; off9 < 9; ++off9) {
        const int ky = off9 / 3;
        const int kx = off9 - ky * 3;
        const char* slab = (const char*)lds + ky * SLAB_B;
        #pragma unroll
        for (int ch = 0; ch < 2; ++ch) {
            bf16x8 a[4];
            #pragma unroll
            for (int mt = 0; mt < 4; ++mt) {
                int col = site_base + mt * 16 + llo + kx;
                int eb = (ch * 64 + lhi * 16) ^ ((col & 7) << 4);
                a[mt] = *reinterpret_cast<const bf16x8*>(slab + col * 128 + eb);
            }
            const __bf16* bb = wt2 + (size_t)(off9 * 8 + ch * 4 + lhi) * (COUT * 8);
            #pragma unroll
            for (int nt = 0; nt < 4; ++nt) {
                bf16x8 bw = *reinterpret_cast<const bf16x8*>(
                    &bb[(co_base + nt * 16 + llo) * 8]);
                #pragma unroll
                for (int mt = 0; mt < 4; ++mt)
                    acc[mt][nt] = __builtin_amdgcn_mfma_f32_16x16x32_bf16(
                        a[mt], bw, acc[mt][nt], 0, 0, 0);
            }
        }
    }

    // D mapping: col(llo)=co, row(lhi*4+q)=site -> reg quad = 4 consecutive x
    #pragma unroll
    for (int nt = 0; nt < 4; ++nt) {
        int co = co_base + nt * 16 + llo;
        float* orow = out + ((size_t)(b * COUT + co) * HH + y) * WW
                          + x0 + site_base + lhi * 4;
        #pragma unroll
        for (int mt = 0; mt < 4; ++mt)
            *reinterpret_cast<f32x4*>(&orow[mt * 16]) = acc[mt][nt];
    }
}

extern "C" void kernel_launch(void* const* d_in, const int* in_sizes, int n_in,
                              void* d_out, int out_size, void* d_ws, size_t ws_size,
                              hipStream_t stream) {
    const float* feat  = (const float*)d_in[0];
    const int*   coors = (const int*)d_in[1];
    const float* w     = (const float*)d_in[3];
    float* out = (float*)d_out;

    const int npts = in_sizes[0] / CIN;   // 200000

    int* cnt = (int*)d_ws;
    int* off = cnt + NBINS;
    int* cur = off + NBINS + 1;
    int* idx = cur + NBINS;
    uintptr_t wa = (uintptr_t)(idx + npts);
    wa = (wa + 15) & ~(uintptr_t)15;
    unsigned short* wt2 = (unsigned short*)wa;

    hipMemsetAsync(cnt, 0, NBINS * sizeof(int), stream);

    int cw_grid = (npts > COUT * 576 ? npts : COUT * 576);
    hipLaunchKernelGGL(count_wt_kernel, dim3((cw_grid + 255) / 256), dim3(256), 0, stream,
                       coors, npts, cnt, w, wt2);
    hipLaunchKernelGGL(scan_kernel, dim3(1), dim3(256), 0, stream,
                       cnt, off, cur);
    hipLaunchKernelGGL(fill_kernel, dim3((npts + 255) / 256), dim3(256), 0, stream,
                       coors, npts, cur, idx);
    hipLaunchKernelGGL(conv_kernel, dim3(NB * HH * NXS), dim3(256), 0, stream,
                       feat, off, idx, (const __bf16*)wt2, out);
}

// Round 11
// 359.033 us; speedup vs baseline: 1.2743x; 1.0075x over previous
//
#include <hip/hip_runtime.h>
#include <stdint.h>

#define HH 512
#define WW 512
#define CIN 64
#define COUT 128
#define NB 4
#define STRIP 128
#define NXS (WW / STRIP)            // 4 x-strips
#define NBINS (NB * HH * NXS)       // 8192 bins: (b, input-row, strip)
#define SCOLS 130                   // staged cols (128 + 2 halo)
#define SLAB_B (SCOLS * CIN * 2)    // 16640 B per row-slab

typedef __bf16 bf16x8 __attribute__((ext_vector_type(8)));
typedef float f32x4 __attribute__((ext_vector_type(4)));

__device__ __forceinline__ unsigned short f2bf(float f) {
    union { float f; uint32_t u; } v; v.f = f;
    uint32_t u = v.u;
    u += 0x7fffu + ((u >> 16) & 1u);   // RNE
    return (unsigned short)(u >> 16);
}
__device__ __forceinline__ float bf2f(uint32_t u) {
    union { uint32_t u; float f; } v; v.u = u << 16;
    return v.f;
}

// Fused: per-bin point count (atomic) + weight transform.
// Wt2 layout: [(k>>3)][co][k&7] bf16, k = (ky*3+kx)*64 + ci.
__global__ void count_wt_kernel(const int* __restrict__ coors, int npts,
                                int* __restrict__ cnt,
                                const float* __restrict__ w,
                                unsigned short* __restrict__ wt2) {
    int t = blockIdx.x * 256 + threadIdx.x;
    if (t < npts) {
        int b = coors[t * 3 + 0];
        int y = coors[t * 3 + 1];
        int x = coors[t * 3 + 2];
        atomicAdd(&cnt[((b << 9) + y) * NXS + (x >> 7)], 1);
    }
    if (t < COUT * 576) {
        int co = t / 576;
        int k  = t - co * 576;
        int off = k >> 6;
        int ci  = k & 63;
        int ky = off / 3;
        int kx = off - ky * 3;
        float val = w[((co * CIN + ci) * 3 + ky) * 3 + kx];
        wt2[(size_t)(k >> 3) * (COUT * 8) + co * 8 + (k & 7)] = f2bf(val);
    }
}

// Exclusive scan of 8192 bin counts -> off[] (+ total) and cur[].
__global__ void scan_kernel(const int* __restrict__ cnt,
                            int* __restrict__ off, int* __restrict__ cur) {
    __shared__ int part[256];
    int t = threadIdx.x;
    int base = t * 32;
    int s = 0;
    for (int i = 0; i < 32; ++i) s += cnt[base + i];
    part[t] = s;
    __syncthreads();
    if (t == 0) {
        int run = 0;
        for (int i = 0; i < 256; ++i) { int v = part[i]; part[i] = run; run += v; }
        off[NBINS] = run;
    }
    __syncthreads();
    int run = part[t];
    for (int i = 0; i < 32; ++i) {
        int bin = base + i;
        int v = cnt[bin];
        off[bin] = run;
        cur[bin] = run;
        run += v;
    }
}

// CSR fill: idx[pos] = point-id | (x << 18)  (p < 2^18, x < 2^9).
__global__ void fill_kernel(const int* __restrict__ coors, int npts,
                            int* __restrict__ cur, int* __restrict__ idx) {
    int p = blockIdx.x * 256 + threadIdx.x;
    if (p >= npts) return;
    int b = coors[p * 3 + 0];
    int y = coors[p * 3 + 1];
    int x = coors[p * 3 + 2];
    int bin = ((b << 9) + y) * NXS + (x >> 7);
    int pos = atomicAdd(&cur[bin], 1);
    idx[pos] = p | (x << 18);
}

// Sparse-direct conv block: (batch, output row y, 128-site strip), all 128 co.
// Gather: per-row wave, coalesced 64-entry CSR chunks, 2 points/step across
// 64 lanes, LDS CAS for duplicates. K-loop v2: weight fragments DOUBLE-
// BUFFERED by off9 (bwA/bwB) — off9=0's loads issued before the gather so
// they complete under its latency; each step issues off9+1's 8 fragments
// then runs the current 16 ds_read + 32 MFMA (L2 latency hidden; R10's
// dependent load->mfma chain was ~16k cyc/wave of exposed stalls).
// Plain f32x4 stores (nt caused 1.3-1.6x write amplification, R6/R8).
__global__ __launch_bounds__(256, 3) void conv_kernel(
        const float* __restrict__ feat,
        const int* __restrict__ off,
        const int* __restrict__ idx,
        const __bf16* __restrict__ wt2,
        float* __restrict__ out) {
    __shared__ __align__(16) __bf16 lds[3 * SCOLS * CIN];

    const int bid = blockIdx.x;
    const int xs = bid & 3;
    const int y  = (bid >> 2) & 511;
    const int b  = bid >> 11;
    const int x0 = xs * STRIP;
    const int tid = threadIdx.x;
    const int wave = tid >> 6;
    const int lane = tid & 63;
    const int lhi = lane >> 4;
    const int llo = lane & 15;
    const int site_base = (wave & 1) * 64;
    const int co_base   = (wave >> 1) * 64;

    // weight-fragment loader for one off9 step: 8 fragments (ch x nt)
    auto ldbw = [&](int o9, bf16x8* dst) {
        #pragma unroll
        for (int ch = 0; ch < 2; ++ch) {
            const __bf16* bb = wt2 + (size_t)(o9 * 8 + ch * 4 + lhi) * (COUT * 8);
            #pragma unroll
            for (int nt = 0; nt < 4; ++nt)
                dst[ch * 4 + nt] = *reinterpret_cast<const bf16x8*>(
                    &bb[(co_base + nt * 16 + llo) * 8]);
        }
    };

    bf16x8 bwA[8], bwB[8];
    ldbw(0, bwA);          // in flight during zero + gather

    // zero all 3 slabs
    {
        const int n16 = 3 * SLAB_B / 16;
        f32x4* l4 = reinterpret_cast<f32x4*>(lds);
        for (int i = tid; i < n16; i += 256)
            l4[i] = (f32x4){0.f, 0.f, 0.f, 0.f};
    }
    __syncthreads();

    // ---- gather: wave r stages input row y-1+r (waves 0..2; wave 3 idle)
    if (wave < 3) {
        const int irow = y - 1 + wave;
        if ((unsigned)irow < HH) {
            char* slab = (char*)lds + wave * SLAB_B;
            const int binrow = ((b << 9) + irow) * NXS;
            const int xlo = xs > 0 ? xs - 1 : 0;
            const int xhi = xs < NXS - 1 ? xs + 1 : xs;
            const int s = off[binrow + xlo];
            const int e = off[binrow + xhi + 1];
            const int hi = lane >> 5;          // which point of the pair
            const int c2 = lane & 31;          // channel-pair
            for (int base = s; base < e; base += 64) {
                const int nchunk = e - base < 64 ? e - base : 64;
                int j = base + lane;
                int v = (j < e) ? idx[j] : 0;  // coalesced chunk load
                #pragma unroll 4
                for (int t = 0; t < 64; t += 2) {
                    if (t >= nchunk) break;
                    int vp = __shfl(v, t + hi);
                    int xp = vp >> 18;
                    int col = xp + 1 - x0;     // window [0, 129]
                    bool ok = (t + hi) < nchunk && (unsigned)col <= 129u;
                    if (ok) {
                        int p = vp & 0x3ffff;
                        float2 f = *reinterpret_cast<const float2*>(
                            &feat[(size_t)p * CIN + c2 * 2]);
                        uint32_t* slot = (uint32_t*)(slab + col * 128
                                                     + ((c2 << 2) ^ ((col & 7) << 4)));
                        uint32_t old = *slot;
                        while (true) {
                            uint32_t nv = (uint32_t)f2bf(bf2f(old & 0xffffu) + f.x)
                                        | ((uint32_t)f2bf(bf2f(old >> 16) + f.y) << 16);
                            uint32_t got = atomicCAS(slot, old, nv);
                            if (got == old) break;
                            old = got;
                        }
                    }
                }
            }
        }
    }
    __syncthreads();

    f32x4 acc[4][4];
    #pragma unroll
    for (int mt = 0; mt < 4; ++mt)
        #pragma unroll
        for (int nt = 0; nt < 4; ++nt)
            acc[mt][nt] = (f32x4){0.f, 0.f, 0.f, 0.f};

    #pragma unroll
    for (int off9 = 0; off9 < 9; ++off9) {
        const int ky = off9 / 3;
        const int kx = off9 - ky * 3;
        const char* slab = (const char*)lds + ky * SLAB_B;
        bf16x8* curw = (off9 & 1) ? bwB : bwA;   // static per unrolled iter
        bf16x8* nxtw = (off9 & 1) ? bwA : bwB;
        if (off9 < 8) ldbw(off9 + 1, nxtw);      // prefetch next step's weights
        #pragma unroll
        for (int ch = 0; ch < 2; ++ch) {
            bf16x8 a[4];
            #pragma unroll
            for (int mt = 0; mt < 4; ++mt) {
                int col = site_base + mt * 16 + llo + kx;
                int eb = (ch * 64 + lhi * 16) ^ ((col & 7) << 4);
                a[mt] = *reinterpret_cast<const bf16x8*>(slab + col * 128 + eb);
            }
            #pragma unroll
            for (int nt = 0; nt < 4; ++nt) {
                #pragma unroll
                for (int mt = 0; mt < 4; ++mt)
                    acc[mt][nt] = __builtin_amdgcn_mfma_f32_16x16x32_bf16(
                        a[mt], curw[ch * 4 + nt], acc[mt][nt], 0, 0, 0);
            }
        }
    }

    // D mapping: col(llo)=co, row(lhi*4+q)=site -> reg quad = 4 consecutive x
    #pragma unroll
    for (int nt = 0; nt < 4; ++nt) {
        int co = co_base + nt * 16 + llo;
        float* orow = out + ((size_t)(b * COUT + co) * HH + y) * WW
                          + x0 + site_base + lhi * 4;
        #pragma unroll
        for (int mt = 0; mt < 4; ++mt)
            *reinterpret_cast<f32x4*>(&orow[mt * 16]) = acc[mt][nt];
    }
}

extern "C" void kernel_launch(void* const* d_in, const int* in_sizes, int n_in,
                              void* d_out, int out_size, void* d_ws, size_t ws_size,
                              hipStream_t stream) {
    const float* feat  = (const float*)d_in[0];
    const int*   coors = (const int*)d_in[1];
    const float* w     = (const float*)d_in[3];
    float* out = (float*)d_out;

    const int npts = in_sizes[0] / CIN;   // 200000

    int* cnt = (int*)d_ws;
    int* off = cnt + NBINS;
    int* cur = off + NBINS + 1;
    int* idx = cur + NBINS;
    uintptr_t wa = (uintptr_t)(idx + npts);
    wa = (wa + 15) & ~(uintptr_t)15;
    unsigned short* wt2 = (unsigned short*)wa;

    hipMemsetAsync(cnt, 0, NBINS * sizeof(int), stream);

    int cw_grid = (npts > COUT * 576 ? npts : COUT * 576);
    hipLaunchKernelGGL(count_wt_kernel, dim3((cw_grid + 255) / 256), dim3(256), 0, stream,
                       coors, npts, cnt, w, wt2);
    hipLaunchKernelGGL(scan_kernel, dim3(1), dim3(256), 0, stream,
                       cnt, off, cur);
    hipLaunchKernelGGL(fill_kernel, dim3((npts + 255) / 256), dim3(256), 0, stream,
                       coors, npts, cur, idx);
    hipLaunchKernelGGL(conv_kernel, dim3(NB * HH * NXS), dim3(256), 0, stream,
                       feat, off, idx, (const __bf16*)wt2, out);
}

// Round 12
// 283.193 us; speedup vs baseline: 1.6156x; 1.2678x over previous
//
#include <hip/hip_runtime.h>
#include <stdint.h>

#define HH 512
#define WW 512
#define CIN 64
#define COUT 128
#define NB 4
#define HP 514          // padded rows: real y at y+1
#define WP 520          // padded cols: real x at x+1
#define STRIP 128       // x-sites per conv block
#define SCOLS 136       // staged cols per slab (130 needed, padded to 17 chunks)
#define NCHUNK 17       // 1024B chunks per slab
#define SLAB_B (SCOLS * CIN * 2)   // 17408 B

typedef __bf16 bf16x8 __attribute__((ext_vector_type(8)));
typedef float f32x4 __attribute__((ext_vector_type(4)));
typedef const __attribute__((address_space(1))) uint32_t guint_t;
typedef __attribute__((address_space(3))) uint32_t luint_t;

__device__ __forceinline__ unsigned short f2bf(float f) {
    union { float f; uint32_t u; } v; v.f = f;
    uint32_t u = v.u;
    u += 0x7fffu + ((u >> 16) & 1u);   // RNE
    return (unsigned short)(u >> 16);
}
__device__ __forceinline__ float bf2f(uint32_t u) {
    union { uint32_t u; float f; } v; v.u = u << 16;
    return v.f;
}

// Fused init: grid-stride zero of padded bf16 dense + weight transform.
// Wt2 layout: [(k>>3)][co][k&7] bf16, k = (ky*3+kx)*64 + ci.
__global__ void init_kernel(float4* __restrict__ dz, long n4,
                            const float* __restrict__ w,
                            unsigned short* __restrict__ wt2) {
    long i = (long)blockIdx.x * 256 + threadIdx.x;
    const long stride = (long)gridDim.x * 256;
    const float4 z = make_float4(0.f, 0.f, 0.f, 0.f);
    for (long j = i; j < n4; j += stride) dz[j] = z;
    int tid = (int)i;
    if (tid < COUT * 576) {
        int co = tid / 576;
        int k  = tid - co * 576;
        int off = k >> 6;
        int ci  = k & 63;
        int ky = off / 3;
        int kx = off - ky * 3;
        float val = w[((co * CIN + ci) * 3 + ky) * 3 + kx];
        wt2[(size_t)(k >> 3) * (COUT * 8) + co * 8 + (k & 7)] = f2bf(val);
    }
}

// Scatter-add into bf16 padded dense via packed-bf16x2 CAS.
__global__ void scatter_kernel(const float* __restrict__ feat,
                               const int* __restrict__ coors,
                               uint32_t* __restrict__ dpad, int npts) {
    int t = blockIdx.x * 256 + threadIdx.x;
    int p = t >> 5;
    int c2 = t & 31;
    if (p >= npts) return;
    int b = coors[p * 3 + 0];
    int y = coors[p * 3 + 1];
    int x = coors[p * 3 + 2];
    uint32_t* wp = dpad + (((size_t)b * HP + (y + 1)) * WP + (x + 1)) * (CIN / 2) + c2;
    float ax = feat[(size_t)p * CIN + c2 * 2];
    float ay = feat[(size_t)p * CIN + c2 * 2 + 1];
    uint32_t old = *wp, assumed;
    do {
        assumed = old;
        uint32_t nv = (uint32_t)f2bf(bf2f(assumed & 0xffffu) + ax)
                    | ((uint32_t)f2bf(bf2f(assumed >> 16) + ay) << 16);
        old = atomicCAS(wp, assumed, nv);
    } while (old != assumed);
}

// One-shot conv block: (batch, output row y, 128-site strip), all 128 co.
// Stage 3 padded rows via global_load_lds (linear LDS dest, inverse-swizzled
// source; ds_read applies the same XOR -> conflict-free, R5-verified).
// K-loop: weight fragments double-buffered by off9 with sched_barrier(0)
// pinning each prefetch issue before the MFMA cluster (R10/R11: dependent
// L2 weight loads ~14k cy/wave were the exposed chain; compiler sank the
// plain-C++ prefetch). Plain f32x4 stores (nt => write amplification, R6/R8).
__global__ __launch_bounds__(256, 3) void conv_kernel(
        const __bf16* __restrict__ dpad,
        const __bf16* __restrict__ wt2,
        float* __restrict__ out) {
    __shared__ __align__(16) __bf16 lds[3 * SCOLS * CIN];

    const int bid = blockIdx.x;
    const int xs = bid & 3;
    const int y  = (bid >> 2) & 511;
    const int b  = bid >> 11;
    const int x0 = xs * STRIP;
    const int tid = threadIdx.x;
    const int wave = tid >> 6;
    const int lane = tid & 63;
    const int lhi = lane >> 4;
    const int llo = lane & 15;
    const int site_base = (wave & 1) * 64;
    const int co_base   = (wave >> 1) * 64;

    // weight-fragment loader for one off9 step: 8 fragments (ch x nt)
    auto ldbw = [&](int o9, bf16x8* dst) {
        #pragma unroll
        for (int ch = 0; ch < 2; ++ch) {
            const __bf16* bb = wt2 + (size_t)(o9 * 8 + ch * 4 + lhi) * (COUT * 8);
            #pragma unroll
            for (int nt = 0; nt < 4; ++nt)
                dst[ch * 4 + nt] = *reinterpret_cast<const bf16x8*>(
                    &bb[(co_base + nt * 16 + llo) * 8]);
        }
    };

    bf16x8 bwA[8], bwB[8];
    ldbw(0, bwA);                              // in flight during staging
    __builtin_amdgcn_sched_barrier(0);         // pin issue before the DMA

    // stage padded rows y..y+2 (= input rows y-1..y+1), cols x0..x0+135
    const char* gbase = (const char*)dpad;
    #pragma unroll
    for (int r = 0; r < 3; ++r) {
        const char* rowp = gbase + (((size_t)b * HP + (y + r)) * WP + x0) * (CIN * 2);
        char* lslab = ((char*)lds) + r * SLAB_B;
        #pragma unroll
        for (int i = 0; i < 5; ++i) {
            int c = wave + i * 4;
            if (c < NCHUNK) {
                int P = c * 1024 + lane * 16;
                int L = P ^ (((P >> 7) & 7) << 4);   // involution on bits 6:4
                __builtin_amdgcn_global_load_lds(
                    (guint_t*)(rowp + L), (luint_t*)(lslab + c * 1024), 16, 0, 0);
            }
        }
    }
    __syncthreads();   // drains vmcnt -> bwA resident, slabs resident

    f32x4 acc[4][4];
    #pragma unroll
    for (int mt = 0; mt < 4; ++mt)
        #pragma unroll
        for (int nt = 0; nt < 4; ++nt)
            acc[mt][nt] = (f32x4){0.f, 0.f, 0.f, 0.f};

    #pragma unroll
    for (int off9 = 0; off9 < 9; ++off9) {
        const int ky = off9 / 3;
        const int kx = off9 - ky * 3;
        const char* slab = (const char*)lds + ky * SLAB_B;
        bf16x8* curw = (off9 & 1) ? bwB : bwA;   // static select (full unroll)
        bf16x8* nxtw = (off9 & 1) ? bwA : bwB;
        if (off9 < 8) ldbw(off9 + 1, nxtw);      // issue next step's 8 loads
        __builtin_amdgcn_sched_barrier(0);       // pin them BEFORE this cluster
        #pragma unroll
        for (int ch = 0; ch < 2; ++ch) {
            bf16x8 a[4];
            #pragma unroll
            for (int mt = 0; mt < 4; ++mt) {
                int col = site_base + mt * 16 + llo + kx;
                int eb = (ch * 64 + lhi * 16) ^ ((col & 7) << 4);
                a[mt] = *reinterpret_cast<const bf16x8*>(slab + col * 128 + eb);
            }
            #pragma unroll
            for (int nt = 0; nt < 4; ++nt) {
                #pragma unroll
                for (int mt = 0; mt < 4; ++mt)
                    acc[mt][nt] = __builtin_amdgcn_mfma_f32_16x16x32_bf16(
                        a[mt], curw[ch * 4 + nt], acc[mt][nt], 0, 0, 0);
            }
        }
    }

    // D mapping: col(llo)=co, row(lhi*4+q)=site -> reg quad = 4 consecutive x
    #pragma unroll
    for (int nt = 0; nt < 4; ++nt) {
        int co = co_base + nt * 16 + llo;
        float* orow = out + ((size_t)(b * COUT + co) * HH + y) * WW
                          + x0 + site_base + lhi * 4;
        #pragma unroll
        for (int mt = 0; mt < 4; ++mt)
            *reinterpret_cast<f32x4*>(&orow[mt * 16]) = acc[mt][nt];
    }
}

extern "C" void kernel_launch(void* const* d_in, const int* in_sizes, int n_in,
                              void* d_out, int out_size, void* d_ws, size_t ws_size,
                              hipStream_t stream) {
    const float* feat  = (const float*)d_in[0];
    const int*   coors = (const int*)d_in[1];
    const float* w     = (const float*)d_in[3];
    float* out = (float*)d_out;

    const size_t dpad_bytes = (size_t)NB * HP * WP * CIN * 2;   // ~137 MB
    __bf16* dpad = (__bf16*)d_ws;
    unsigned short* wt2 = (unsigned short*)((char*)d_ws + dpad_bytes);

    const int npts = in_sizes[0] / CIN; // 200000

    hipLaunchKernelGGL(init_kernel, dim3(2048), dim3(256), 0, stream,
                       (float4*)dpad, (long)(dpad_bytes / 16), w, wt2);
    hipLaunchKernelGGL(scatter_kernel, dim3((npts * 32 + 255) / 256), dim3(256), 0, stream,
                       feat, coors, (uint32_t*)dpad, npts);
    hipLaunchKernelGGL(conv_kernel, dim3(NB * 512 * (WW / STRIP)), dim3(256), 0, stream,
                       dpad, (const __bf16*)wt2, out);
}